// Round 7
// baseline (425.146 us; speedup 1.0000x reference)
//
#include <hip/hip_runtime.h>

#define B_   2
#define T_   2048
#define D_   2048
#define H_   16
#define KVH_ 4
#define DH_  128
#define WIN_ 1024
#define N_TOT 5120   // q(2048) | k(512) | v(512) | g(2048) concatenated output cols

typedef __attribute__((ext_vector_type(4))) float    f32x4;
typedef __attribute__((ext_vector_type(8))) _Float16 half8;
typedef __attribute__((ext_vector_type(8))) short    short8;
typedef __attribute__((ext_vector_type(4))) short    short4v;

// fp32 -> fp16 (RTN via hardware cvt). fp16 chosen over bf16: scores S ~ N(0,7.6^2)
// amplify q/k relative error through softmax; bf16's 2^-9 rounding gave absmax 0.86.
__device__ __forceinline__ unsigned short f2h(float f) {
    _Float16 h = (_Float16)f;
    return __builtin_bit_cast(unsigned short, h);
}

__device__ __forceinline__ f32x4 mfma16x16x32(short8 a, short8 b, f32x4 c) {
    return __builtin_amdgcn_mfma_f32_16x16x32_f16(
        __builtin_bit_cast(half8, a), __builtin_bit_cast(half8, b), c, 0, 0, 0);
}

// async global->LDS, 16B per lane (dest must be wave-uniform base + lane*16)
__device__ __forceinline__ void glds16(const void* g, void* l) {
    __builtin_amdgcn_global_load_lds(
        (const __attribute__((address_space(1))) unsigned int*)g,
        (__attribute__((address_space(3))) unsigned int*)l, 16, 0, 0);
}

// ---------------------------------------------------------------- RoPE tables
__global__ void rope_tab_kernel(float* __restrict__ cosT, float* __restrict__ sinT) {
    int idx = blockIdx.x * 256 + threadIdx.x;
    if (idx >= T_ * 64) return;
    int t = idx >> 6, i = idx & 63;
    float inv = powf(10000.0f, -(float)i / 64.0f);
    float f = (float)t * inv;
    cosT[idx] = cosf(f);
    sinT[idx] = sinf(f);
}

// ---------------------------------------------------------------- x: fp32 -> fp16 (same layout)
__global__ void xconv_kernel(const float* __restrict__ xf, unsigned short* __restrict__ xb) {
    int idx = blockIdx.x * 256 + threadIdx.x;      // 8 elements per thread
    float4 f0 = ((const float4*)xf)[idx * 2];
    float4 f1 = ((const float4*)xf)[idx * 2 + 1];
    unsigned p0 = f2h(f0.x) | ((unsigned)f2h(f0.y) << 16);
    unsigned p1 = f2h(f0.z) | ((unsigned)f2h(f0.w) << 16);
    unsigned p2 = f2h(f1.x) | ((unsigned)f2h(f1.y) << 16);
    unsigned p3 = f2h(f1.z) | ((unsigned)f2h(f1.w) << 16);
    ((uint4*)xb)[idx] = make_uint4(p0, p1, p2, p3);
}

// ---------------------------------------------------------------- W[k][n] fp32 -> WT[n][k] fp16 (64x64 LDS tile transpose)
__global__ __launch_bounds__(256) void wtconv_kernel(
    const float* __restrict__ W, unsigned short* __restrict__ WTdst, int nW) {
    __shared__ unsigned short tile[64][72];   // pad 72: rows 144B (16B aligned)
    int ntiles_n = nW >> 6;
    int n0 = (blockIdx.x % ntiles_n) * 64;
    int k0 = (blockIdx.x / ntiles_n) * 64;
    int tid = threadIdx.x;
    {   // read 64x64 fp32 coalesced, convert, store to LDS
        int kr = tid >> 2, c0 = (tid & 3) * 16;
        const float* src = W + (size_t)(k0 + kr) * nW + n0 + c0;
        float4 a = ((const float4*)src)[0], b = ((const float4*)src)[1];
        float4 c = ((const float4*)src)[2], d = ((const float4*)src)[3];
        uint4 lo = make_uint4(f2h(a.x) | ((unsigned)f2h(a.y) << 16),
                              f2h(a.z) | ((unsigned)f2h(a.w) << 16),
                              f2h(b.x) | ((unsigned)f2h(b.y) << 16),
                              f2h(b.z) | ((unsigned)f2h(b.w) << 16));
        uint4 hi = make_uint4(f2h(c.x) | ((unsigned)f2h(c.y) << 16),
                              f2h(c.z) | ((unsigned)f2h(c.w) << 16),
                              f2h(d.x) | ((unsigned)f2h(d.y) << 16),
                              f2h(d.z) | ((unsigned)f2h(d.w) << 16));
        *(uint4*)(&tile[kr][c0])     = lo;
        *(uint4*)(&tile[kr][c0 + 8]) = hi;
    }
    __syncthreads();
    {   // write transposed rows, 32B per thread
        int nr = tid >> 2, kc = (tid & 3) * 16;
        unsigned short vals[16];
        #pragma unroll
        for (int j = 0; j < 16; ++j) vals[j] = tile[kc + j][nr];
        uint4 lo = *(uint4*)(&vals[0]);
        uint4 hi = *(uint4*)(&vals[8]);
        unsigned short* dst = WTdst + (size_t)(n0 + nr) * D_ + k0 + kc;
        *(uint4*)(dst)     = lo;
        *(uint4*)(dst + 8) = hi;
    }
}

// ---------------------------------------------------------------- fused GEMM: C[4096][5120] = xh * WT^T  (m97 structure)
__global__ __launch_bounds__(256) void gemm_bt_kernel(
    const unsigned short* __restrict__ Ab, const unsigned short* __restrict__ Bt,
    float* __restrict__ C) {
    __shared__ unsigned short As[128 * 64];
    __shared__ unsigned short Bs[128 * 64];
    const int tid = threadIdx.x;
    const int l = tid & 63, w = tid >> 6;
    const int wr = w >> 1, wc = w & 1;
    // XCD-aware bijective swizzle: 1280 blocks = 8 XCDs x 160
    int swz = (blockIdx.x & 7) * 160 + (blockIdx.x >> 3);
    const int mb0 = (swz / 40) * 128, nb0 = (swz % 40) * 128;

    f32x4 acc[4][4] = {};

    for (int k0 = 0; k0 < D_; k0 += 64) {
        __syncthreads();
        #pragma unroll
        for (int r = 0; r < 4; ++r) {
            int idx = r * 256 + tid;
            int m = idx >> 3, u = idx & 7;           // m: 0..127, u: 16B chunk in row
            glds16(Ab + (size_t)(mb0 + m) * D_ + k0 + u * 8, &As[idx * 8]);
            glds16(Bt + (size_t)(nb0 + m) * D_ + k0 + u * 8, &Bs[idx * 8]);
        }
        __syncthreads();   // compiler emits vmcnt(0) drain before barrier
        #pragma unroll
        for (int ks = 0; ks < 2; ++ks) {
            short8 af[4], bfr[4];
            #pragma unroll
            for (int mi = 0; mi < 4; ++mi)
                af[mi] = *(const short8*)(&As[(wr * 64 + mi * 16 + (l & 15)) * 64 + ks * 32 + (l >> 4) * 8]);
            #pragma unroll
            for (int ni = 0; ni < 4; ++ni)
                bfr[ni] = *(const short8*)(&Bs[(wc * 64 + ni * 16 + (l & 15)) * 64 + ks * 32 + (l >> 4) * 8]);
            #pragma unroll
            for (int mi = 0; mi < 4; ++mi)
                #pragma unroll
                for (int ni = 0; ni < 4; ++ni)
                    acc[mi][ni] = mfma16x16x32(af[mi], bfr[ni], acc[mi][ni]);
        }
    }
    // C/D layout: col = lane&15 (n), row = (lane>>4)*4 + i (m)   [verified m89/m91]
    #pragma unroll
    for (int mi = 0; mi < 4; ++mi)
        #pragma unroll
        for (int ni = 0; ni < 4; ++ni)
            #pragma unroll
            for (int i = 0; i < 4; ++i)
                C[(size_t)(mb0 + wr * 64 + mi * 16 + (l >> 4) * 4 + i) * N_TOT
                  + nb0 + wc * 64 + ni * 16 + (l & 15)] = acc[mi][ni][i];
}

// ---------------------------------------------------------------- q/k post: rmsnorm + rope (+q scale), fp32 -> fp16, relayout [b][h][t][dh]
__global__ __launch_bounds__(256) void qk_post_kernel(
    const float* __restrict__ C, int colofs, unsigned short* __restrict__ dst,
    const float* __restrict__ cosT, const float* __restrict__ sinT,
    const float* __restrict__ sscale, int nheads, int is_q) {
    int rid = blockIdx.x * 4 + (threadIdx.x >> 6);
    int lane = threadIdx.x & 63;
    int h = rid % nheads;
    int t = (rid / nheads) % T_;
    int b = rid / (nheads * T_);
    const float* row = C + (size_t)(b * T_ + t) * N_TOT + colofs + h * 128;
    float x1 = row[lane], x2 = row[lane + 64];
    float ss = x1 * x1 + x2 * x2;
    #pragma unroll
    for (int m = 1; m < 64; m <<= 1) ss += __shfl_xor(ss, m);
    float rn = rsqrtf(ss * (1.0f / 128.0f) + 1e-6f);
    float c = cosT[t * 64 + lane], s = sinT[t * 64 + lane];
    float y1 = x1 * c + x2 * s;
    float y2 = x2 * c - x1 * s;
    float sc = rn;
    if (is_q) sc *= sscale[h] * logf((float)(t + 1)) * 0.08838834764831845f; // * 1/sqrt(DH)
    y1 *= sc; y2 *= sc;
    unsigned short* drow = dst + ((size_t)(b * nheads + h) * T_ + t) * 128;
    drow[lane]      = f2h(y1);
    drow[lane + 64] = f2h(y2);
}

// ---------------------------------------------------------------- v: fp32 -> fp16, relayout [b][kv][t][dh], 8 elems/thread
__global__ void vconv_kernel(const float* __restrict__ C, unsigned short* __restrict__ vb) {
    int idx = blockIdx.x * 256 + threadIdx.x;   // 262144 threads
    int c8  = idx & 15;            // 8-elem chunk within head dim
    int kvh = (idx >> 4) & 3;
    int t   = (idx >> 6) & 2047;
    int b   = idx >> 17;
    const float* src = C + (size_t)(b * T_ + t) * N_TOT + 2560 + kvh * 128 + c8 * 8;
    float4 f0 = ((const float4*)src)[0];
    float4 f1 = ((const float4*)src)[1];
    unsigned p0 = f2h(f0.x) | ((unsigned)f2h(f0.y) << 16);
    unsigned p1 = f2h(f0.z) | ((unsigned)f2h(f0.w) << 16);
    unsigned p2 = f2h(f1.x) | ((unsigned)f2h(f1.y) << 16);
    unsigned p3 = f2h(f1.z) | ((unsigned)f2h(f1.w) << 16);
    unsigned short* dst = vb + ((size_t)(b * KVH_ + kvh) * T_ + t) * 128 + c8 * 8;
    *(uint4*)dst = make_uint4(p0, p1, p2, p3);
}

// ---------------------------------------------------------------- flash attention (windowed causal, GQA)
__global__ __launch_bounds__(256) void attn_kernel(
    const unsigned short* __restrict__ Q, const unsigned short* __restrict__ K,
    const unsigned short* __restrict__ V, float* __restrict__ O) {
    __shared__ __align__(16) char smem[34816];
    unsigned short* Kl = (unsigned short*)smem;            // [64][128] fp16, XOR-swizzled
    unsigned short* Vt = (unsigned short*)smem + 64 * 136; // [128][68] fp16 (V^T)

    const int tid = threadIdx.x, l = tid & 63, w = tid >> 6;
    const int qbi = blockIdx.x & 31, h = (blockIdx.x >> 5) & 15, b = blockIdx.x >> 9;
    const int qb = qbi * 64, kvh = h >> 2;
    const unsigned short* Qp = Q + (size_t)(b * H_ + h) * T_ * 128;
    const unsigned short* Kp = K + (size_t)(b * KVH_ + kvh) * T_ * 128;
    const unsigned short* Vp = V + (size_t)(b * KVH_ + kvh) * T_ * 128;
    const int qw = qb + w * 16;          // this wave's 16 q rows
    const int qi = qw + (l & 15);        // this lane's q row (col of S^T)

    short8 qfr[4];
    #pragma unroll
    for (int dk = 0; dk < 4; ++dk)
        qfr[dk] = *(const short8*)(Qp + (size_t)(qw + (l & 15)) * 128 + dk * 32 + (l >> 4) * 8);

    f32x4 Oa[8] = {};          // O^T tiles: d = dt*16 + (l>>4)*4 + i, q = l&15
    float mrun = -1e30f, lrun = 0.0f;

    const int k0 = (qb - WIN_ > 0) ? (qb - WIN_) : 0;
    for (int tile = k0; tile <= qb; tile += 64) {
        __syncthreads();
        // stage K tile [64][128] -> Kl with XOR swizzle (G4: byte ^= (row&7)<<4)
        #pragma unroll
        for (int r = 0; r < 4; ++r) {
            int uidx = tid + 256 * r;
            int key = uidx >> 4, u = uidx & 15;
            int4 val = *(const int4*)(Kp + (size_t)(tile + key) * 128 + u * 8);
            int byte = (key * 256 + u * 16) ^ ((key & 7) << 4);
            *(int4*)((char*)Kl + byte) = val;
        }
        // stage V tile transposed -> Vt[128][68]
        {
            int kb = tid >> 4, db = tid & 15;
            unsigned short vr[4][8];
            #pragma unroll
            for (int ki = 0; ki < 4; ++ki)
                *(int4*)vr[ki] = *(const int4*)(Vp + (size_t)(tile + kb * 4 + ki) * 128 + db * 8);
            #pragma unroll
            for (int di = 0; di < 8; ++di) {
                unsigned lo = vr[0][di] | ((unsigned)vr[1][di] << 16);
                unsigned hi = vr[2][di] | ((unsigned)vr[3][di] << 16);
                *(uint2*)(&Vt[(db * 8 + di) * 68 + kb * 4]) = make_uint2(lo, hi);
            }
        }
        __syncthreads();

        #pragma unroll
        for (int pair = 0; pair < 2; ++pair) {
            int kp = tile + pair * 32;
            if (kp > qw + 15) continue;            // fully above causal for this wave
            if (kp + 31 < qw - WIN_) continue;     // fully below window

            // S^T = K_tile * Q^T  (swapped operands: acc col = q, row = key)
            f32x4 s0 = {}, s1 = {};
            __builtin_amdgcn_s_setprio(1);         // T5: favor MFMA wave (m191 +4-7%)
            #pragma unroll
            for (int dk = 0; dk < 4; ++dk) {
                int r0 = pair * 32 + (l & 15), r1 = r0 + 16;
                int c  = dk * 64 + (l >> 4) * 16;
                short8 kf0 = *(const short8*)((char*)Kl + ((r0 * 256 + c) ^ ((r0 & 7) << 4)));
                short8 kf1 = *(const short8*)((char*)Kl + ((r1 * 256 + c) ^ ((r1 & 7) << 4)));
                s0 = mfma16x16x32(kf0, qfr[dk], s0);
                s1 = mfma16x16x32(kf1, qfr[dk], s1);
            }
            __builtin_amdgcn_s_setprio(0);
            // mask + online softmax (per-q state replicated across the 4 lane-groups)
            float smax = -1e30f;
            #pragma unroll
            for (int i = 0; i < 4; ++i) {
                int ki0 = kp + (l >> 4) * 4 + i;
                int ki1 = ki0 + 16;
                if (ki0 > qi || qi - ki0 > WIN_) s0[i] = -1e30f;
                if (ki1 > qi || qi - ki1 > WIN_) s1[i] = -1e30f;
                smax = fmaxf(smax, fmaxf(s0[i], s1[i]));
            }
            smax = fmaxf(smax, __shfl_xor(smax, 16));
            smax = fmaxf(smax, __shfl_xor(smax, 32));
            // T13 defer-max (THR=8): skip O-rescale while running max is within e^8.
            // exp(S-mrun) <= e^8 = 2981 fits fp16 (max 65504).
            if (!__all(smax <= mrun + 8.0f)) {
                float mnew = fmaxf(mrun, smax);
                float alpha = __expf(mrun - mnew);
                lrun *= alpha;
                #pragma unroll
                for (int dt = 0; dt < 8; ++dt) Oa[dt] *= alpha;
                mrun = mnew;
            }
            float psum = 0.0f;
            short8 pb;
            #pragma unroll
            for (int i = 0; i < 4; ++i) {
                float p0 = __expf(s0[i] - mrun);
                float p1 = __expf(s1[i] - mrun);
                psum += p0 + p1;
                pb[i]     = (short)f2h(p0);
                pb[i + 4] = (short)f2h(p1);
            }
            psum += __shfl_xor(psum, 16);
            psum += __shfl_xor(psum, 32);
            lrun += psum;
            // O^T += V^T * P  (P comes straight from the S^T accumulator layout)
            __builtin_amdgcn_s_setprio(1);
            #pragma unroll
            for (int dt = 0; dt < 8; ++dt) {
                union { short4v hlf[2]; short8 v8; } vu;
                vu.hlf[0] = *(const short4v*)(&Vt[(dt * 16 + (l & 15)) * 68 + pair * 32 +      (l >> 4) * 4]);
                vu.hlf[1] = *(const short4v*)(&Vt[(dt * 16 + (l & 15)) * 68 + pair * 32 + 16 + (l >> 4) * 4]);
                Oa[dt] = mfma16x16x32(vu.v8, pb, Oa[dt]);
            }
            __builtin_amdgcn_s_setprio(0);
        }
    }

    // finalize + coalesced store via per-wave LDS transpose (reuse smem)
    __syncthreads();
    float* Ow = (float*)smem + w * (16 * 132);
    float inv = 1.0f / lrun;
    #pragma unroll
    for (int dt = 0; dt < 8; ++dt)
        #pragma unroll
        for (int i = 0; i < 4; ++i)
            Ow[(l & 15) * 132 + dt * 16 + (l >> 4) * 4 + i] = Oa[dt][i] * inv;
    #pragma unroll
    for (int j = 0; j < 8; ++j) {
        int idx4 = l + 64 * j;
        int row = idx4 >> 5, dpos = (idx4 & 31) * 4;
        float4 val = *(const float4*)(&Ow[row * 132 + dpos]);
        *(float4*)(O + ((size_t)(b * H_ + h) * T_ + qw + row) * 128 + dpos) = val;
    }
}

// ---------------------------------------------------------------- epilogue: y = rmsnorm(o * silu(g)) * gn_weight
__global__ __launch_bounds__(256) void gate_norm_kernel(
    const float* __restrict__ o, const float* __restrict__ C,
    const float* __restrict__ gnw, float* __restrict__ out) {
    int rid = blockIdx.x * 4 + (threadIdx.x >> 6);   // (b,t,h)
    int lane = threadIdx.x & 63;
    int h = rid & 15;
    int t = (rid >> 4) & 2047;
    int b = rid >> 15;
    const float* orow = o + ((size_t)(b * H_ + h) * T_ + t) * 128;
    const float* grow = C + (size_t)(b * T_ + t) * N_TOT + 3072 + h * 128;
    float o1 = orow[lane], o2 = orow[lane + 64];
    float g1 = grow[lane], g2 = grow[lane + 64];
    float y1 = o1 * (g1 / (1.0f + __expf(-g1)));
    float y2 = o2 * (g2 / (1.0f + __expf(-g2)));
    float ss = y1 * y1 + y2 * y2;
    #pragma unroll
    for (int m = 1; m < 64; m <<= 1) ss += __shfl_xor(ss, m);
    float rn = rsqrtf(ss * (1.0f / 128.0f) + 1e-6f);
    float* wrow = out + (size_t)rid * 128;
    wrow[lane]      = y1 * rn * gnw[lane];
    wrow[lane + 64] = y2 * rn * gnw[lane + 64];
}

// ---------------------------------------------------------------- launch
extern "C" void kernel_launch(void* const* d_in, const int* in_sizes, int n_in,
                              void* d_out, int out_size, void* d_ws, size_t ws_size,
                              hipStream_t stream) {
    const float* x      = (const float*)d_in[0];
    const float* Wq     = (const float*)d_in[1];
    const float* Wk     = (const float*)d_in[2];
    const float* Wv     = (const float*)d_in[3];
    const float* Wg     = (const float*)d_in[4];
    const float* sscale = (const float*)d_in[5];
    const float* gnw    = (const float*)d_in[6];
    float* out = (float*)d_out;

    char* ws = (char*)d_ws;
    unsigned short* xh16 = (unsigned short*)(ws);                 // [0, 16M)
    unsigned short* WT   = (unsigned short*)(ws + 16777216);      // [16M, 36M)  5120x2048 fp16
    float*          C    = (float*)(ws + 37748736);               // [36M, 116M) 4096x5120 fp32
    unsigned short* qh16 = (unsigned short*)(ws + 121634816);     // 16 MB
    unsigned short* kh16 = (unsigned short*)(ws + 138412032);     //  4 MB
    unsigned short* vh16 = (unsigned short*)(ws + 142606336);     //  4 MB
    float*          cosT = (float*)(ws + 146800640);              //  0.5 MB
    float*          sinT = (float*)(ws + 147324928);              //  0.5 MB
    float*          o    = (float*)(ws);   // aliases xh16+WT (dead after GEMM), 32 MB

    rope_tab_kernel<<<512, 256, 0, stream>>>(cosT, sinT);

    xconv_kernel<<<4096, 256, 0, stream>>>(x, xh16);
    wtconv_kernel<<<1024, 256, 0, stream>>>(Wq, WT,                       2048);
    wtconv_kernel<<<256,  256, 0, stream>>>(Wk, WT + (size_t)2048 * D_,   512);
    wtconv_kernel<<<256,  256, 0, stream>>>(Wv, WT + (size_t)2560 * D_,   512);
    wtconv_kernel<<<1024, 256, 0, stream>>>(Wg, WT + (size_t)3072 * D_,   2048);

    gemm_bt_kernel<<<1280, 256, 0, stream>>>(xh16, WT, C);

    qk_post_kernel<<<16384, 256, 0, stream>>>(C, 0,    qh16, cosT, sinT, sscale, H_,   1);
    qk_post_kernel<<<4096,  256, 0, stream>>>(C, 2048, kh16, cosT, sinT, sscale, KVH_, 0);
    vconv_kernel<<<1024, 256, 0, stream>>>(C, vh16);

    attn_kernel<<<B_ * H_ * (T_ / 64), 256, 0, stream>>>(qh16, kh16, vh16, o);

    gate_norm_kernel<<<16384, 256, 0, stream>>>(o, C, gnw, out);
}

// Round 8
// 413.013 us; speedup vs baseline: 1.0294x; 1.0294x over previous
//
#include <hip/hip_runtime.h>

#define B_   2
#define T_   2048
#define D_   2048
#define H_   16
#define KVH_ 4
#define DH_  128
#define WIN_ 1024
#define N_TOT 5120   // q(2048) | k(512) | v(512) | g(2048) concatenated output cols

typedef __attribute__((ext_vector_type(4))) float    f32x4;
typedef __attribute__((ext_vector_type(8))) _Float16 half8;
typedef __attribute__((ext_vector_type(8))) short    short8;
typedef __attribute__((ext_vector_type(4))) short    short4v;

// fp32 -> fp16 (RTN via hardware cvt). fp16 over bf16: scores S ~ N(0,7.6^2)
// amplify q/k relative error through softmax; bf16 rounding gave absmax 0.86.
__device__ __forceinline__ unsigned short f2h(float f) {
    _Float16 h = (_Float16)f;
    return __builtin_bit_cast(unsigned short, h);
}

__device__ __forceinline__ f32x4 mfma16x16x32(short8 a, short8 b, f32x4 c) {
    return __builtin_amdgcn_mfma_f32_16x16x32_f16(
        __builtin_bit_cast(half8, a), __builtin_bit_cast(half8, b), c, 0, 0, 0);
}

// async global->LDS, 16B per lane (dest must be wave-uniform base + lane*16)
__device__ __forceinline__ void glds16(const void* g, void* l) {
    __builtin_amdgcn_global_load_lds(
        (const __attribute__((address_space(1))) unsigned int*)g,
        (__attribute__((address_space(3))) unsigned int*)l, 16, 0, 0);
}

// ---------------------------------------------------------------- RoPE tables
__global__ void rope_tab_kernel(float* __restrict__ cosT, float* __restrict__ sinT) {
    int idx = blockIdx.x * 256 + threadIdx.x;
    if (idx >= T_ * 64) return;
    int t = idx >> 6, i = idx & 63;
    float inv = powf(10000.0f, -(float)i / 64.0f);
    float f = (float)t * inv;
    cosT[idx] = cosf(f);
    sinT[idx] = sinf(f);
}

// ---------------------------------------------------------------- x: fp32 -> fp16 (same layout)
__global__ void xconv_kernel(const float* __restrict__ xf, unsigned short* __restrict__ xb) {
    int idx = blockIdx.x * 256 + threadIdx.x;      // 8 elements per thread
    float4 f0 = ((const float4*)xf)[idx * 2];
    float4 f1 = ((const float4*)xf)[idx * 2 + 1];
    unsigned p0 = f2h(f0.x) | ((unsigned)f2h(f0.y) << 16);
    unsigned p1 = f2h(f0.z) | ((unsigned)f2h(f0.w) << 16);
    unsigned p2 = f2h(f1.x) | ((unsigned)f2h(f1.y) << 16);
    unsigned p3 = f2h(f1.z) | ((unsigned)f2h(f1.w) << 16);
    ((uint4*)xb)[idx] = make_uint4(p0, p1, p2, p3);
}

// ---------------------------------------------------------------- W[k][n] fp32 -> WT[n][k] fp16 (64x64 LDS tile transpose)
__global__ __launch_bounds__(256) void wtconv_kernel(
    const float* __restrict__ W, unsigned short* __restrict__ WTdst, int nW) {
    __shared__ unsigned short tile[64][72];   // pad 72: rows 144B (16B aligned)
    int ntiles_n = nW >> 6;
    int n0 = (blockIdx.x % ntiles_n) * 64;
    int k0 = (blockIdx.x / ntiles_n) * 64;
    int tid = threadIdx.x;
    {   // read 64x64 fp32 coalesced, convert, store to LDS
        int kr = tid >> 2, c0 = (tid & 3) * 16;
        const float* src = W + (size_t)(k0 + kr) * nW + n0 + c0;
        float4 a = ((const float4*)src)[0], b = ((const float4*)src)[1];
        float4 c = ((const float4*)src)[2], d = ((const float4*)src)[3];
        uint4 lo = make_uint4(f2h(a.x) | ((unsigned)f2h(a.y) << 16),
                              f2h(a.z) | ((unsigned)f2h(a.w) << 16),
                              f2h(b.x) | ((unsigned)f2h(b.y) << 16),
                              f2h(b.z) | ((unsigned)f2h(b.w) << 16));
        uint4 hi = make_uint4(f2h(c.x) | ((unsigned)f2h(c.y) << 16),
                              f2h(c.z) | ((unsigned)f2h(c.w) << 16),
                              f2h(d.x) | ((unsigned)f2h(d.y) << 16),
                              f2h(d.z) | ((unsigned)f2h(d.w) << 16));
        *(uint4*)(&tile[kr][c0])     = lo;
        *(uint4*)(&tile[kr][c0 + 8]) = hi;
    }
    __syncthreads();
    {   // write transposed rows, 32B per thread
        int nr = tid >> 2, kc = (tid & 3) * 16;
        unsigned short vals[16];
        #pragma unroll
        for (int j = 0; j < 16; ++j) vals[j] = tile[kc + j][nr];
        uint4 lo = *(uint4*)(&vals[0]);
        uint4 hi = *(uint4*)(&vals[8]);
        unsigned short* dst = WTdst + (size_t)(n0 + nr) * D_ + k0 + kc;
        *(uint4*)(dst)     = lo;
        *(uint4*)(dst + 8) = hi;
    }
}

// ---------------------------------------------------------------- fused GEMM: C[4096][5120] = xh * WT^T
// 8-phase 256x256 schedule (T3+T4 counted vmcnt, T5 setprio), k-half-major LDS
// layout [buf][mat][kh][256*32] fp16 (64B rows -> conflict-free ds_read_b128).
// Per iteration j: phases P1-P4 compute tile 2j (buf0), P5-P8 tile 2j+1 (buf1).
// Each phase stages exactly the 16KB region freed 2 barriers earlier.
// vmcnt(4) only at P4/P8 ends; raw s_barrier (no vmcnt(0) drain).
#define LDSOFF(d,s,kh) ((((d)*2+(s))*2+(kh))*8192)
#define LDA_(d,qk,mf) (*(const short8*)(&ldsbuf[LDSOFF(d,0,qk) + (wm*128 + (mf)*16 + lr)*32 + lg*8]))
#define LDB_(d,qk,nf) (*(const short8*)(&ldsbuf[LDSOFF(d,1,qk) + (wn*64  + (nf)*16 + lr)*32 + lg*8]))
#define STAGE(d,s,kh,tile,base,R0) do { \
    _Pragma("unroll") \
    for (int ll = 0; ll < 2; ++ll) { \
      int c_ = ll*512 + tid; \
      int rr_ = c_ >> 2, sl_ = c_ & 3; \
      glds16((base) + (size_t)((R0) + rr_) * D_ + (tile)*64 + (kh)*32 + sl_*8, \
             &ldsbuf[LDSOFF(d,s,kh) + c_*8]); \
    } \
  } while (0)
#define SBAR do { __builtin_amdgcn_sched_barrier(0); __builtin_amdgcn_s_barrier(); } while (0)
#define MFMA_CLUSTER(QN2) do { \
    __builtin_amdgcn_s_setprio(1); \
    _Pragma("unroll") \
    for (int mf = 0; mf < 8; ++mf) { \
      acc[mf][(QN2)*2]   = mfma16x16x32(af[mf], bf0, acc[mf][(QN2)*2]); \
      acc[mf][(QN2)*2+1] = mfma16x16x32(af[mf], bf1, acc[mf][(QN2)*2+1]); \
    } \
    __builtin_amdgcn_s_setprio(0); \
  } while (0)

__global__ __launch_bounds__(512, 2) void gemm8_kernel(
    const unsigned short* __restrict__ Ab, const unsigned short* __restrict__ Bt,
    float* __restrict__ C) {
    __shared__ unsigned short ldsbuf[65536];   // 128 KiB
    const int tid = threadIdx.x;
    const int lr = tid & 15, lg = (tid >> 4) & 3;
    const int wid = tid >> 6;
    const int wm = wid >> 2, wn = wid & 3;
    // XCD-aware bijective swizzle: 320 blocks = 8 XCDs x 40
    int swz = (blockIdx.x & 7) * 40 + (blockIdx.x >> 3);
    const int MB0 = (swz / 20) * 256, NB0 = (swz % 20) * 256;

    f32x4 acc[8][4] = {};

    // prologue: fully stage tiles 0 (buf0) and 1 (buf1); wait for tile 0
    STAGE(0,0,0, 0, Ab, MB0);  STAGE(0,1,0, 0, Bt, NB0);
    STAGE(0,0,1, 0, Ab, MB0);  STAGE(0,1,1, 0, Bt, NB0);
    STAGE(1,0,0, 1, Ab, MB0);  STAGE(1,1,0, 1, Bt, NB0);
    STAGE(1,0,1, 1, Ab, MB0);  STAGE(1,1,1, 1, Bt, NB0);
    asm volatile("s_waitcnt vmcnt(8)" ::: "memory");
    __builtin_amdgcn_s_barrier();

    for (int j = 0; j < 16; ++j) {
        const int tO = 2*j + 1;
        const bool sP = (j >= 1);    // stage tile 2j+1 kh1 halves (j=0: pre-staged)
        const bool sN = (j < 15);    // tiles 2j+2 / 2j+3 exist
        short8 af[8], bf0, bf1;
        // ---- P1: buf0 qk=0 qn2=0
        #pragma unroll
        for (int mf = 0; mf < 8; ++mf) af[mf] = LDA_(0,0,mf);
        bf0 = LDB_(0,0,0); bf1 = LDB_(0,0,1);
        if (sP) STAGE(1,0,1, tO, Ab, MB0);
        SBAR; MFMA_CLUSTER(0); SBAR;
        // ---- P2: buf0 qk=0 qn2=1 (af reused)
        bf0 = LDB_(0,0,2); bf1 = LDB_(0,0,3);
        if (sP) STAGE(1,1,1, tO, Bt, NB0);
        SBAR; MFMA_CLUSTER(1); SBAR;
        // ---- P3: buf0 qk=1 qn2=0
        #pragma unroll
        for (int mf = 0; mf < 8; ++mf) af[mf] = LDA_(0,1,mf);
        bf0 = LDB_(0,1,0); bf1 = LDB_(0,1,1);
        if (sN) STAGE(0,0,0, 2*j+2, Ab, MB0);
        SBAR; MFMA_CLUSTER(0); SBAR;
        // ---- P4: buf0 qk=1 qn2=1  (wait: tile 2j+1 fully landed)
        bf0 = LDB_(0,1,2); bf1 = LDB_(0,1,3);
        if (sN) STAGE(0,1,0, 2*j+2, Bt, NB0);
        __builtin_amdgcn_sched_barrier(0); __builtin_amdgcn_s_barrier();
        MFMA_CLUSTER(1);
        if (sN) asm volatile("s_waitcnt vmcnt(4)" ::: "memory");
        else    asm volatile("s_waitcnt vmcnt(0)" ::: "memory");
        SBAR;
        // ---- P5: buf1 qk=0 qn2=0
        #pragma unroll
        for (int mf = 0; mf < 8; ++mf) af[mf] = LDA_(1,0,mf);
        bf0 = LDB_(1,0,0); bf1 = LDB_(1,0,1);
        if (sN) STAGE(0,0,1, 2*j+2, Ab, MB0);
        SBAR; MFMA_CLUSTER(0); SBAR;
        // ---- P6: buf1 qk=0 qn2=1
        bf0 = LDB_(1,0,2); bf1 = LDB_(1,0,3);
        if (sN) STAGE(0,1,1, 2*j+2, Bt, NB0);
        SBAR; MFMA_CLUSTER(1); SBAR;
        // ---- P7: buf1 qk=1 qn2=0
        #pragma unroll
        for (int mf = 0; mf < 8; ++mf) af[mf] = LDA_(1,1,mf);
        bf0 = LDB_(1,1,0); bf1 = LDB_(1,1,1);
        if (sN) STAGE(1,0,0, 2*j+3, Ab, MB0);
        SBAR; MFMA_CLUSTER(0); SBAR;
        // ---- P8: buf1 qk=1 qn2=1  (wait: tile 2j+2 fully landed)
        bf0 = LDB_(1,1,2); bf1 = LDB_(1,1,3);
        if (sN) STAGE(1,1,0, 2*j+3, Bt, NB0);
        __builtin_amdgcn_sched_barrier(0); __builtin_amdgcn_s_barrier();
        MFMA_CLUSTER(1);
        if (sN) asm volatile("s_waitcnt vmcnt(4)" ::: "memory");
        else    asm volatile("s_waitcnt vmcnt(0)" ::: "memory");
        SBAR;
    }

    // epilogue: C/D layout col = lane&15 (n), row = (lane>>4)*4 + i (m)
    #pragma unroll
    for (int mf = 0; mf < 8; ++mf)
        #pragma unroll
        for (int nf = 0; nf < 4; ++nf)
            #pragma unroll
            for (int i = 0; i < 4; ++i)
                C[(size_t)(MB0 + wm*128 + mf*16 + lg*4 + i) * N_TOT
                  + NB0 + wn*64 + nf*16 + lr] = acc[mf][nf][i];
}

// ---------------------------------------------------------------- q/k post: rmsnorm + rope (+q scale), fp32 -> fp16, relayout [b][h][t][dh]
__global__ __launch_bounds__(256) void qk_post_kernel(
    const float* __restrict__ C, int colofs, unsigned short* __restrict__ dst,
    const float* __restrict__ cosT, const float* __restrict__ sinT,
    const float* __restrict__ sscale, int nheads, int is_q) {
    int rid = blockIdx.x * 4 + (threadIdx.x >> 6);
    int lane = threadIdx.x & 63;
    int h = rid % nheads;
    int t = (rid / nheads) % T_;
    int b = rid / (nheads * T_);
    const float* row = C + (size_t)(b * T_ + t) * N_TOT + colofs + h * 128;
    float x1 = row[lane], x2 = row[lane + 64];
    float ss = x1 * x1 + x2 * x2;
    #pragma unroll
    for (int m = 1; m < 64; m <<= 1) ss += __shfl_xor(ss, m);
    float rn = rsqrtf(ss * (1.0f / 128.0f) + 1e-6f);
    float c = cosT[t * 64 + lane], s = sinT[t * 64 + lane];
    float y1 = x1 * c + x2 * s;
    float y2 = x2 * c - x1 * s;
    float sc = rn;
    if (is_q) sc *= sscale[h] * logf((float)(t + 1)) * 0.08838834764831845f; // * 1/sqrt(DH)
    y1 *= sc; y2 *= sc;
    unsigned short* drow = dst + ((size_t)(b * nheads + h) * T_ + t) * 128;
    drow[lane]      = f2h(y1);
    drow[lane + 64] = f2h(y2);
}

// ---------------------------------------------------------------- v: fp32 -> fp16, relayout [b][kv][t][dh], 8 elems/thread
__global__ void vconv_kernel(const float* __restrict__ C, unsigned short* __restrict__ vb) {
    int idx = blockIdx.x * 256 + threadIdx.x;   // 262144 threads
    int c8  = idx & 15;            // 8-elem chunk within head dim
    int kvh = (idx >> 4) & 3;
    int t   = (idx >> 6) & 2047;
    int b   = idx >> 17;
    const float* src = C + (size_t)(b * T_ + t) * N_TOT + 2560 + kvh * 128 + c8 * 8;
    float4 f0 = ((const float4*)src)[0];
    float4 f1 = ((const float4*)src)[1];
    unsigned p0 = f2h(f0.x) | ((unsigned)f2h(f0.y) << 16);
    unsigned p1 = f2h(f0.z) | ((unsigned)f2h(f0.w) << 16);
    unsigned p2 = f2h(f1.x) | ((unsigned)f2h(f1.y) << 16);
    unsigned p3 = f2h(f1.z) | ((unsigned)f2h(f1.w) << 16);
    unsigned short* dst = vb + ((size_t)(b * KVH_ + kvh) * T_ + t) * 128 + c8 * 8;
    *(uint4*)dst = make_uint4(p0, p1, p2, p3);
}

// ---------------------------------------------------------------- flash attention (windowed causal, GQA)
__global__ __launch_bounds__(256) void attn_kernel(
    const unsigned short* __restrict__ Q, const unsigned short* __restrict__ K,
    const unsigned short* __restrict__ V, float* __restrict__ O) {
    __shared__ __align__(16) char smem[34816];
    unsigned short* Kl = (unsigned short*)smem;            // [64][128] fp16, XOR-swizzled
    unsigned short* Vt = (unsigned short*)smem + 64 * 136; // [128][68] fp16 (V^T)

    const int tid = threadIdx.x, l = tid & 63, w = tid >> 6;
    const int qbi = blockIdx.x & 31, h = (blockIdx.x >> 5) & 15, b = blockIdx.x >> 9;
    const int qb = qbi * 64, kvh = h >> 2;
    const unsigned short* Qp = Q + (size_t)(b * H_ + h) * T_ * 128;
    const unsigned short* Kp = K + (size_t)(b * KVH_ + kvh) * T_ * 128;
    const unsigned short* Vp = V + (size_t)(b * KVH_ + kvh) * T_ * 128;
    const int qw = qb + w * 16;          // this wave's 16 q rows
    const int qi = qw + (l & 15);        // this lane's q row (col of S^T)

    short8 qfr[4];
    #pragma unroll
    for (int dk = 0; dk < 4; ++dk)
        qfr[dk] = *(const short8*)(Qp + (size_t)(qw + (l & 15)) * 128 + dk * 32 + (l >> 4) * 8);

    f32x4 Oa[8] = {};          // O^T tiles: d = dt*16 + (l>>4)*4 + i, q = l&15
    float mrun = -1e30f, lrun = 0.0f;

    const int k0 = (qb - WIN_ > 0) ? (qb - WIN_) : 0;
    for (int tile = k0; tile <= qb; tile += 64) {
        __syncthreads();
        // stage K tile [64][128] -> Kl with XOR swizzle (G4: byte ^= (row&7)<<4)
        #pragma unroll
        for (int r = 0; r < 4; ++r) {
            int uidx = tid + 256 * r;
            int key = uidx >> 4, u = uidx & 15;
            int4 val = *(const int4*)(Kp + (size_t)(tile + key) * 128 + u * 8);
            int byte = (key * 256 + u * 16) ^ ((key & 7) << 4);
            *(int4*)((char*)Kl + byte) = val;
        }
        // stage V tile transposed -> Vt[128][68]
        {
            int kb = tid >> 4, db = tid & 15;
            unsigned short vr[4][8];
            #pragma unroll
            for (int ki = 0; ki < 4; ++ki)
                *(int4*)vr[ki] = *(const int4*)(Vp + (size_t)(tile + kb * 4 + ki) * 128 + db * 8);
            #pragma unroll
            for (int di = 0; di < 8; ++di) {
                unsigned lo = vr[0][di] | ((unsigned)vr[1][di] << 16);
                unsigned hi = vr[2][di] | ((unsigned)vr[3][di] << 16);
                *(uint2*)(&Vt[(db * 8 + di) * 68 + kb * 4]) = make_uint2(lo, hi);
            }
        }
        __syncthreads();

        #pragma unroll
        for (int pair = 0; pair < 2; ++pair) {
            int kp = tile + pair * 32;
            if (kp > qw + 15) continue;            // fully above causal for this wave
            if (kp + 31 < qw - WIN_) continue;     // fully below window

            // S^T = K_tile * Q^T  (swapped operands: acc col = q, row = key)
            f32x4 s0 = {}, s1 = {};
            __builtin_amdgcn_s_setprio(1);         // T5: favor MFMA wave (m191 +4-7%)
            #pragma unroll
            for (int dk = 0; dk < 4; ++dk) {
                int r0 = pair * 32 + (l & 15), r1 = r0 + 16;
                int c  = dk * 64 + (l >> 4) * 16;
                short8 kf0 = *(const short8*)((char*)Kl + ((r0 * 256 + c) ^ ((r0 & 7) << 4)));
                short8 kf1 = *(const short8*)((char*)Kl + ((r1 * 256 + c) ^ ((r1 & 7) << 4)));
                s0 = mfma16x16x32(kf0, qfr[dk], s0);
                s1 = mfma16x16x32(kf1, qfr[dk], s1);
            }
            __builtin_amdgcn_s_setprio(0);
            // mask + online softmax (per-q state replicated across the 4 lane-groups)
            float smax = -1e30f;
            #pragma unroll
            for (int i = 0; i < 4; ++i) {
                int ki0 = kp + (l >> 4) * 4 + i;
                int ki1 = ki0 + 16;
                if (ki0 > qi || qi - ki0 > WIN_) s0[i] = -1e30f;
                if (ki1 > qi || qi - ki1 > WIN_) s1[i] = -1e30f;
                smax = fmaxf(smax, fmaxf(s0[i], s1[i]));
            }
            smax = fmaxf(smax, __shfl_xor(smax, 16));
            smax = fmaxf(smax, __shfl_xor(smax, 32));
            // T13 defer-max (THR=8): skip O-rescale while running max is within e^8.
            // exp(S-mrun) <= e^8 = 2981 fits fp16 (max 65504).
            if (!__all(smax <= mrun + 8.0f)) {
                float mnew = fmaxf(mrun, smax);
                float alpha = __expf(mrun - mnew);
                lrun *= alpha;
                #pragma unroll
                for (int dt = 0; dt < 8; ++dt) Oa[dt] *= alpha;
                mrun = mnew;
            }
            float psum = 0.0f;
            short8 pb;
            #pragma unroll
            for (int i = 0; i < 4; ++i) {
                float p0 = __expf(s0[i] - mrun);
                float p1 = __expf(s1[i] - mrun);
                psum += p0 + p1;
                pb[i]     = (short)f2h(p0);
                pb[i + 4] = (short)f2h(p1);
            }
            psum += __shfl_xor(psum, 16);
            psum += __shfl_xor(psum, 32);
            lrun += psum;
            // O^T += V^T * P  (P comes straight from the S^T accumulator layout)
            __builtin_amdgcn_s_setprio(1);
            #pragma unroll
            for (int dt = 0; dt < 8; ++dt) {
                union { short4v hlf[2]; short8 v8; } vu;
                vu.hlf[0] = *(const short4v*)(&Vt[(dt * 16 + (l & 15)) * 68 + pair * 32 +      (l >> 4) * 4]);
                vu.hlf[1] = *(const short4v*)(&Vt[(dt * 16 + (l & 15)) * 68 + pair * 32 + 16 + (l >> 4) * 4]);
                Oa[dt] = mfma16x16x32(vu.v8, pb, Oa[dt]);
            }
            __builtin_amdgcn_s_setprio(0);
        }
    }

    // finalize + coalesced store via per-wave LDS transpose (reuse smem)
    __syncthreads();
    float* Ow = (float*)smem + w * (16 * 132);
    float inv = 1.0f / lrun;
    #pragma unroll
    for (int dt = 0; dt < 8; ++dt)
        #pragma unroll
        for (int i = 0; i < 4; ++i)
            Ow[(l & 15) * 132 + dt * 16 + (l >> 4) * 4 + i] = Oa[dt][i] * inv;
    #pragma unroll
    for (int j = 0; j < 8; ++j) {
        int idx4 = l + 64 * j;
        int row = idx4 >> 5, dpos = (idx4 & 31) * 4;
        float4 val = *(const float4*)(&Ow[row * 132 + dpos]);
        *(float4*)(O + ((size_t)(b * H_ + h) * T_ + qw + row) * 128 + dpos) = val;
    }
}

// ---------------------------------------------------------------- epilogue: y = rmsnorm(o * silu(g)) * gn_weight
__global__ __launch_bounds__(256) void gate_norm_kernel(
    const float* __restrict__ o, const float* __restrict__ C,
    const float* __restrict__ gnw, float* __restrict__ out) {
    int rid = blockIdx.x * 4 + (threadIdx.x >> 6);   // (b,t,h)
    int lane = threadIdx.x & 63;
    int h = rid & 15;
    int t = (rid >> 4) & 2047;
    int b = rid >> 15;
    const float* orow = o + ((size_t)(b * H_ + h) * T_ + t) * 128;
    const float* grow = C + (size_t)(b * T_ + t) * N_TOT + 3072 + h * 128;
    float o1 = orow[lane], o2 = orow[lane + 64];
    float g1 = grow[lane], g2 = grow[lane + 64];
    float y1 = o1 * (g1 / (1.0f + __expf(-g1)));
    float y2 = o2 * (g2 / (1.0f + __expf(-g2)));
    float ss = y1 * y1 + y2 * y2;
    #pragma unroll
    for (int m = 1; m < 64; m <<= 1) ss += __shfl_xor(ss, m);
    float rn = rsqrtf(ss * (1.0f / 128.0f) + 1e-6f);
    float* wrow = out + (size_t)rid * 128;
    wrow[lane]      = y1 * rn * gnw[lane];
    wrow[lane + 64] = y2 * rn * gnw[lane + 64];
}

// ---------------------------------------------------------------- launch
extern "C" void kernel_launch(void* const* d_in, const int* in_sizes, int n_in,
                              void* d_out, int out_size, void* d_ws, size_t ws_size,
                              hipStream_t stream) {
    const float* x      = (const float*)d_in[0];
    const float* Wq     = (const float*)d_in[1];
    const float* Wk     = (const float*)d_in[2];
    const float* Wv     = (const float*)d_in[3];
    const float* Wg     = (const float*)d_in[4];
    const float* sscale = (const float*)d_in[5];
    const float* gnw    = (const float*)d_in[6];
    float* out = (float*)d_out;

    char* ws = (char*)d_ws;
    unsigned short* xh16 = (unsigned short*)(ws);                 // [0, 16M)
    unsigned short* WT   = (unsigned short*)(ws + 16777216);      // [16M, 36M)  5120x2048 fp16
    float*          C    = (float*)(ws + 37748736);               // [36M, 116M) 4096x5120 fp32
    unsigned short* qh16 = (unsigned short*)(ws + 121634816);     // 16 MB
    unsigned short* kh16 = (unsigned short*)(ws + 138412032);     //  4 MB
    unsigned short* vh16 = (unsigned short*)(ws + 142606336);     //  4 MB
    float*          cosT = (float*)(ws + 146800640);              //  0.5 MB
    float*          sinT = (float*)(ws + 147324928);              //  0.5 MB
    float*          o    = (float*)(ws);   // aliases xh16+WT (dead after GEMM), 32 MB

    rope_tab_kernel<<<512, 256, 0, stream>>>(cosT, sinT);

    xconv_kernel<<<4096, 256, 0, stream>>>(x, xh16);
    wtconv_kernel<<<1024, 256, 0, stream>>>(Wq, WT,                       2048);
    wtconv_kernel<<<256,  256, 0, stream>>>(Wk, WT + (size_t)2048 * D_,   512);
    wtconv_kernel<<<256,  256, 0, stream>>>(Wv, WT + (size_t)2560 * D_,   512);
    wtconv_kernel<<<1024, 256, 0, stream>>>(Wg, WT + (size_t)3072 * D_,   2048);

    gemm8_kernel<<<320, 512, 0, stream>>>(xh16, WT, C);

    qk_post_kernel<<<16384, 256, 0, stream>>>(C, 0,    qh16, cosT, sinT, sscale, H_,   1);
    qk_post_kernel<<<4096,  256, 0, stream>>>(C, 2048, kh16, cosT, sinT, sscale, KVH_, 0);
    vconv_kernel<<<1024, 256, 0, stream>>>(C, vh16);

    attn_kernel<<<B_ * H_ * (T_ / 64), 256, 0, stream>>>(qh16, kh16, vh16, o);

    gate_norm_kernel<<<16384, 256, 0, stream>>>(o, C, gnw, out);
}